// Round 1
// baseline (720.173 us; speedup 1.0000x reference)
//
#include <hip/hip_runtime.h>
#include <math.h>

#define N_NODES 50000
#define C_IN 128
#define C_HID 128
#define C_OUT 64
#define BN_EPS 1e-5f

// ---------------- degree histogram ----------------
__global__ void k_deg(const int* __restrict__ dst, int* __restrict__ deg, int E) {
    int e = blockIdx.x * 256 + threadIdx.x;
    if (e < E) atomicAdd(&deg[dst[e]], 1);
}

// ---------------- exclusive scan (single block), dinv, cursor ----------------
__global__ __launch_bounds__(1024) void k_scan(const int* __restrict__ deg,
                                               int* __restrict__ rowstart,
                                               int* __restrict__ cursor,
                                               float* __restrict__ dinv, int n) {
    __shared__ int part[1024];
    int tid = threadIdx.x;
    const int CH = (n + 1023) / 1024;
    int lo = tid * CH;
    int hi = lo + CH; if (hi > n) hi = n;
    int s = 0;
    for (int i = lo; i < hi; ++i) s += deg[i];
    part[tid] = s;
    __syncthreads();
    for (int off = 1; off < 1024; off <<= 1) {
        int val = (tid >= off) ? part[tid - off] : 0;
        __syncthreads();
        part[tid] += val;
        __syncthreads();
    }
    int run = (tid == 0) ? 0 : part[tid - 1];
    for (int i = lo; i < hi; ++i) {
        int d = deg[i];
        rowstart[i] = run;
        cursor[i] = run;
        dinv[i] = rsqrtf((float)(d + 1));   // +1 self-loop
        run += d;
    }
    if (tid == 1023) rowstart[n] = part[1023];
}

// ---------------- CSR fill ----------------
__global__ void k_fill(const int* __restrict__ src, const int* __restrict__ dst,
                       int* __restrict__ cursor, int* __restrict__ csr, int E) {
    int e = blockIdx.x * 256 + threadIdx.x;
    if (e < E) {
        int pos = atomicAdd(&cursor[dst[e]], 1);
        csr[pos] = src[e];
    }
}

// ---------------- GEMM1: h = x @ W1  (n x 128 @ 128 x 128) ----------------
__global__ __launch_bounds__(256) void k_gemm1(const float* __restrict__ x,
                                               const float* __restrict__ W,
                                               float* __restrict__ h, int n) {
    __shared__ float WT[C_IN * 132];   // WT[col*132 + k], padded stride
    __shared__ float xs[8][C_IN];
    for (int i = threadIdx.x; i < C_IN * C_IN; i += 256) {
        int k = i >> 7, c = i & 127;
        WT[c * 132 + k] = W[i];
    }
    __syncthreads();
    int col = threadIdx.x & 127;
    int half = threadIdx.x >> 7;
    for (int base = blockIdx.x * 8; base < n; base += gridDim.x * 8) {
        for (int i = threadIdx.x; i < 8 * C_IN; i += 256) {
            int r = i >> 7, c = i & 127;
            int row = base + r;
            xs[r][c] = (row < n) ? x[row * C_IN + c] : 0.f;
        }
        __syncthreads();
        float acc[4] = {0.f, 0.f, 0.f, 0.f};
        int r0 = half * 4;
        for (int k = 0; k < C_IN; k += 4) {
            float4 w4 = *(const float4*)&WT[col * 132 + k];
            #pragma unroll
            for (int r = 0; r < 4; ++r) {
                float4 x4 = *(const float4*)&xs[r0 + r][k];
                acc[r] += w4.x * x4.x + w4.y * x4.y + w4.z * x4.z + w4.w * x4.w;
            }
        }
        #pragma unroll
        for (int r = 0; r < 4; ++r) {
            int row = base + r0 + r;
            if (row < n) h[row * C_HID + col] = acc[r];
        }
        __syncthreads();
    }
}

// ---------------- gather layer1: g1[v] = b1 + dinv[v]^2 h[v] + sum dinv[s]dinv[v] h[s] ----------------
__global__ __launch_bounds__(256) void k_gather1(const float* __restrict__ h,
                                                 const float* __restrict__ dinv,
                                                 const int* __restrict__ rowstart,
                                                 const int* __restrict__ csr,
                                                 const float* __restrict__ b,
                                                 float* __restrict__ out, int n) {
    int v = (blockIdx.x * 256 + threadIdx.x) >> 6;
    int lane = threadIdx.x & 63;
    if (v >= n) return;
    float dv = dinv[v];
    int s0 = rowstart[v], s1 = rowstart[v + 1];
    float2 acc;
    {
        float2 hv = *(const float2*)&h[v * C_HID + lane * 2];
        float w = dv * dv;
        acc.x = hv.x * w; acc.y = hv.y * w;
    }
    for (int e = s0; e < s1; ++e) {
        int s = csr[e];
        float w = dinv[s] * dv;
        float2 hs = *(const float2*)&h[s * C_HID + lane * 2];
        acc.x += hs.x * w; acc.y += hs.y * w;
    }
    float2 bb = *(const float2*)&b[lane * 2];
    acc.x += bb.x; acc.y += bb.y;
    *(float2*)&out[v * C_HID + lane * 2] = acc;
}

// ---------------- BN stats ----------------
__global__ __launch_bounds__(256) void k_bnstats(const float* __restrict__ g,
                                                 float* __restrict__ gsum,
                                                 float* __restrict__ gss, int n) {
    float s = 0.f, ss = 0.f;
    int stride = gridDim.x * 256;
    int total = n * C_HID;
    for (int i = blockIdx.x * 256 + threadIdx.x; i < total; i += stride) {
        float v = g[i];
        s += v; ss += v * v;
    }
    __shared__ float ls[256], lss[256];
    ls[threadIdx.x] = s; lss[threadIdx.x] = ss;
    __syncthreads();
    if (threadIdx.x < 128) {
        atomicAdd(&gsum[threadIdx.x], ls[threadIdx.x] + ls[threadIdx.x + 128]);
        atomicAdd(&gss[threadIdx.x], lss[threadIdx.x] + lss[threadIdx.x + 128]);
    }
}

__global__ void k_bnfin(const float* __restrict__ gsum, const float* __restrict__ gss,
                        const float* __restrict__ gamma, const float* __restrict__ beta,
                        float* __restrict__ scale, float* __restrict__ shift, int n) {
    int c = threadIdx.x;
    if (c < C_HID) {
        float inv_n = 1.f / (float)n;
        float mean = gsum[c] * inv_n;
        float var = gss[c] * inv_n - mean * mean;
        float sc = gamma[c] * rsqrtf(var + BN_EPS);
        scale[c] = sc;
        shift[c] = beta[c] - mean * sc;
    }
}

// ---------------- GEMM2 fused BN+ELU: h2 = elu(g1*scale+shift) @ W2 ----------------
__global__ __launch_bounds__(256) void k_gemm2(const float* __restrict__ g1,
                                               const float* __restrict__ W2,
                                               const float* __restrict__ scale,
                                               const float* __restrict__ shift,
                                               float* __restrict__ h2, int n) {
    __shared__ float WT[C_OUT * 132];   // WT[col*132 + k]
    __shared__ float ys[16][C_HID];
    __shared__ float sc[C_HID], sh[C_HID];
    for (int i = threadIdx.x; i < C_HID * C_OUT; i += 256) {
        int k = i >> 6, c = i & 63;
        WT[c * 132 + k] = W2[i];
    }
    if (threadIdx.x < C_HID) {
        sc[threadIdx.x] = scale[threadIdx.x];
        sh[threadIdx.x] = shift[threadIdx.x];
    }
    __syncthreads();
    int col = threadIdx.x & 63;
    int q = threadIdx.x >> 6;   // 0..3
    for (int base = blockIdx.x * 16; base < n; base += gridDim.x * 16) {
        for (int i = threadIdx.x; i < 16 * C_HID; i += 256) {
            int r = i >> 7, c = i & 127;
            int row = base + r;
            float v = (row < n) ? g1[row * C_HID + c] : 0.f;
            v = v * sc[c] + sh[c];
            ys[r][c] = v > 0.f ? v : expm1f(v);
        }
        __syncthreads();
        float acc[4] = {0.f, 0.f, 0.f, 0.f};
        int r0 = q * 4;
        for (int k = 0; k < C_HID; k += 4) {
            float4 w4 = *(const float4*)&WT[col * 132 + k];
            #pragma unroll
            for (int r = 0; r < 4; ++r) {
                float4 x4 = *(const float4*)&ys[r0 + r][k];
                acc[r] += w4.x * x4.x + w4.y * x4.y + w4.z * x4.z + w4.w * x4.w;
            }
        }
        #pragma unroll
        for (int r = 0; r < 4; ++r) {
            int row = base + r0 + r;
            if (row < n) h2[row * C_OUT + col] = acc[r];
        }
        __syncthreads();
    }
}

// ---------------- gather layer2: out = b2 + dinv^2 h2[v] + sum dinv dinv h2[s] ----------------
__global__ __launch_bounds__(256) void k_gather2(const float* __restrict__ h,
                                                 const float* __restrict__ dinv,
                                                 const int* __restrict__ rowstart,
                                                 const int* __restrict__ csr,
                                                 const float* __restrict__ b,
                                                 float* __restrict__ out, int n) {
    int v = (blockIdx.x * 256 + threadIdx.x) >> 6;
    int lane = threadIdx.x & 63;
    if (v >= n) return;
    float dv = dinv[v];
    int s0 = rowstart[v], s1 = rowstart[v + 1];
    float acc = h[v * C_OUT + lane] * dv * dv;
    for (int e = s0; e < s1; ++e) {
        int s = csr[e];
        float w = dinv[s] * dv;
        acc += h[s * C_OUT + lane] * w;
    }
    out[v * C_OUT + lane] = acc + b[lane];
}

// ---------------- launch ----------------
extern "C" void kernel_launch(void* const* d_in, const int* in_sizes, int n_in,
                              void* d_out, int out_size, void* d_ws, size_t ws_size,
                              hipStream_t stream) {
    const float* x     = (const float*)d_in[0];
    const int*   ei    = (const int*)d_in[1];
    const float* W1    = (const float*)d_in[2];
    const float* b1    = (const float*)d_in[3];
    const float* gamma = (const float*)d_in[4];
    const float* beta  = (const float*)d_in[5];
    const float* W2    = (const float*)d_in[6];
    const float* b2    = (const float*)d_in[7];
    float* out = (float*)d_out;

    const int n = in_sizes[0] / C_IN;     // 50000
    const int E = in_sizes[1] / 2;        // 800000
    const int* src = ei;
    const int* dst = ei + E;

    // workspace carve (256B aligned)
    char* p = (char*)d_ws;
    auto carve = [&](size_t bytes) {
        char* r = p;
        p += (bytes + 255) & ~(size_t)255;
        return r;
    };
    int*   deg      = (int*)  carve((size_t)n * 4);
    int*   rowstart = (int*)  carve((size_t)(n + 1) * 4);
    int*   cursor   = (int*)  carve((size_t)n * 4);
    int*   csr      = (int*)  carve((size_t)E * 4);
    float* dinv     = (float*)carve((size_t)n * 4);
    float* h1       = (float*)carve((size_t)n * C_HID * 4);
    float* g1       = (float*)carve((size_t)n * C_HID * 4);
    float* h2       = (float*)carve((size_t)n * C_OUT * 4);
    float* gsum     = (float*)carve(C_HID * 4);
    float* gss      = (float*)carve(C_HID * 4);
    float* scale    = (float*)carve(C_HID * 4);
    float* shift    = (float*)carve(C_HID * 4);

    hipMemsetAsync(deg, 0, (size_t)n * 4, stream);
    hipMemsetAsync(gsum, 0, C_HID * 4, stream);
    hipMemsetAsync(gss, 0, C_HID * 4, stream);

    int eblocks = (E + 255) / 256;
    k_deg<<<eblocks, 256, 0, stream>>>(dst, deg, E);
    k_gemm1<<<(n + 7) / 8, 256, 0, stream>>>(x, W1, h1, n);
    k_scan<<<1, 1024, 0, stream>>>(deg, rowstart, cursor, dinv, n);
    k_fill<<<eblocks, 256, 0, stream>>>(src, dst, cursor, csr, E);
    k_gather1<<<(n * 64 + 255) / 256, 256, 0, stream>>>(h1, dinv, rowstart, csr, b1, g1, n);
    k_bnstats<<<512, 256, 0, stream>>>(g1, gsum, gss, n);
    k_bnfin<<<1, 128, 0, stream>>>(gsum, gss, gamma, beta, scale, shift, n);
    k_gemm2<<<(n + 15) / 16, 256, 0, stream>>>(g1, W2, scale, shift, h2, n);
    k_gather2<<<(n * 64 + 255) / 256, 256, 0, stream>>>(h2, dinv, rowstart, csr, b2, out, n);
}